// Round 13
// baseline (1580.245 us; speedup 1.0000x reference)
//
#include <hip/hip_runtime.h>
#include <hip/hip_fp16.h>
#include <math.h>

#define NEG_SLOPE 0.2f

__device__ __forceinline__ float lrelu(float x) { return x > 0.f ? x : NEG_SLOPE * x; }

// Order-preserving float<->uint encoding so unsigned atomicMax == float max.
__device__ __forceinline__ unsigned encf(float f) {
    unsigned u = __float_as_uint(f);
    return (u & 0x80000000u) ? ~u : (u | 0x80000000u);
}
__device__ __forceinline__ float decf(unsigned u) {
    return __uint_as_float((u & 0x80000000u) ? (u ^ 0x80000000u) : ~u);
}

// Phase A + dst-histogram (merged). Grid MUST be G=256 blocks x 512 threads:
// counts[j*G + blockIdx] layout is shared with scatterS.
__global__ void __launch_bounds__(512)
phaseAH(const float* __restrict__ x, const float* __restrict__ W1,
        const float* __restrict__ a_src, const float* __restrict__ a_dst,
        const int* __restrict__ dst,
        __half* __restrict__ h1h, float* __restrict__ asrc1,
        float* __restrict__ adst1, float* __restrict__ eloop1,
        int* __restrict__ counts, unsigned* __restrict__ gmax1,
        unsigned* __restrict__ gmax2, int N, int E, int nbuck) {
    __shared__ int hist[1024];
    int tid = threadIdx.x;
    for (int j = tid; j < nbuck; j += 512) hist[j] = 0;
    if (blockIdx.x == 0 && tid < 5) {
        if (tid < 4) gmax1[tid] = 0u;
        else gmax2[0] = 0u;
    }
    __syncthreads();

    // histogram over this block's edge slice
    int per = (E + gridDim.x - 1) / gridDim.x;
    int i0 = blockIdx.x * per, i1 = min(E, i0 + per);
    for (int i = i0 + tid; i < i1; i += 512)
        atomicAdd(&hist[dst[i] >> 7], 1);

    // phaseA over this block's node slice (wave per node)
    int npb = (N + gridDim.x - 1) / gridDim.x;
    int n0 = blockIdx.x * npb, n1 = min(N, n0 + npb);
    int lane = tid & 63;
    int head = lane >> 4, c = lane & 15;
    for (int node = n0 + (tid >> 6); node < n1; node += 8) {
        float h = 0.f;
        #pragma unroll
        for (int k = 0; k < 7; k++) h += x[node * 7 + k] * W1[k * 64 + lane];

        float ho = __shfl_xor(h, 1);
        if (!(lane & 1)) {
            __half2 hp = __floats2half2_rn(h, ho);
            ((__half2*)h1h)[(size_t)node * 32 + (lane >> 1)] = hp;
        }

        float s = h * a_src[lane];
        float d = h * a_dst[lane];
        #pragma unroll
        for (int m = 8; m >= 1; m >>= 1) {
            s += __shfl_xor(s, m);
            d += __shfl_xor(d, m);
        }
        if (c == 0) {
            asrc1[node * 4 + head] = s;
            adst1[node * 4 + head] = d;
            eloop1[node * 4 + head] = lrelu(s + d);
        }
    }
    __syncthreads();
    for (int j = tid; j < nbuck; j += 512)
        counts[j * gridDim.x + blockIdx.x] = hist[j];
}

// Global per-head max of asrc1 [N,4] -> gmax1[4] (encoded).
__global__ void gmax1K(const float* __restrict__ asrc1, unsigned* __restrict__ gmax1, int N) {
    float m0 = -1e30f, m1 = -1e30f, m2 = -1e30f, m3 = -1e30f;
    for (int i = blockIdx.x * blockDim.x + threadIdx.x; i < N; i += gridDim.x * blockDim.x) {
        float4 v = ((const float4*)asrc1)[i];
        m0 = fmaxf(m0, v.x); m1 = fmaxf(m1, v.y);
        m2 = fmaxf(m2, v.z); m3 = fmaxf(m3, v.w);
    }
    #pragma unroll
    for (int mm = 32; mm >= 1; mm >>= 1) {
        m0 = fmaxf(m0, __shfl_xor(m0, mm));
        m1 = fmaxf(m1, __shfl_xor(m1, mm));
        m2 = fmaxf(m2, __shfl_xor(m2, mm));
        m3 = fmaxf(m3, __shfl_xor(m3, mm));
    }
    if ((threadIdx.x & 63) == 0) {
        atomicMax(&gmax1[0], encf(m0));
        atomicMax(&gmax1[1], encf(m1));
        atomicMax(&gmax1[2], encf(m2));
        atomicMax(&gmax1[3], encf(m3));
    }
}

__global__ void gmax2K(const float* __restrict__ asrc2, unsigned* __restrict__ gmax2, int N) {
    float m0 = -1e30f;
    for (int i = blockIdx.x * blockDim.x + threadIdx.x; i < N; i += gridDim.x * blockDim.x)
        m0 = fmaxf(m0, asrc2[i]);
    #pragma unroll
    for (int mm = 32; mm >= 1; mm >>= 1) m0 = fmaxf(m0, __shfl_xor(m0, mm));
    if ((threadIdx.x & 63) == 0) atomicMax(gmax2, encf(m0));
}

// Generic exclusive scan, 3 kernels (n up to 262144).
__global__ void scan1(const int* __restrict__ in, int* __restrict__ outv,
                      int* __restrict__ blockSum, int n) {
    __shared__ int sm[256];
    int tid = threadIdx.x;
    int i = blockIdx.x * 256 + tid;
    int v = (i < n) ? in[i] : 0;
    sm[tid] = v;
    __syncthreads();
    for (int off = 1; off < 256; off <<= 1) {
        int t = sm[tid];
        int add = (tid >= off) ? sm[tid - off] : 0;
        __syncthreads();
        sm[tid] = t + add;
        __syncthreads();
    }
    if (i < n) outv[i] = sm[tid] - v;     // exclusive
    if (tid == 255) blockSum[blockIdx.x] = sm[255];
}

__global__ void scan2(int* __restrict__ blockSum, int nb) {
    __shared__ int sm[1024];
    int tid = threadIdx.x;
    int v = (tid < nb) ? blockSum[tid] : 0;
    sm[tid] = v;
    __syncthreads();
    for (int off = 1; off < 1024; off <<= 1) {
        int t = sm[tid];
        int add = (tid >= off) ? sm[tid - off] : 0;
        __syncthreads();
        sm[tid] = t + add;
        __syncthreads();
    }
    if (tid < nb) blockSum[tid] = sm[tid] - v;  // exclusive
}

__global__ void scan3(int* __restrict__ outv, const int* __restrict__ blockSum, int n) {
    int i = blockIdx.x * 256 + threadIdx.x;
    if (i < n) outv[i] += blockSum[blockIdx.x];
}

// scatterS: LDS cursors seeded from scanned offsets; LDS atomics only.
// ebuf entry packed: src (17b) | local-node-id (7b) << 17.
__global__ void scatterS(const int* __restrict__ src, const int* __restrict__ dst,
                         const int* __restrict__ ocounts, int* __restrict__ ebuf,
                         int E, int nbuck) {
    __shared__ int cur[1024];
    for (int j = threadIdx.x; j < nbuck; j += blockDim.x)
        cur[j] = ocounts[j * gridDim.x + blockIdx.x];
    __syncthreads();
    int per = (E + gridDim.x - 1) / gridDim.x;
    int i0 = blockIdx.x * per, i1 = min(E, i0 + per);
    for (int i = i0 + threadIdx.x; i < i1; i += blockDim.x) {
        int d = dst[i];
        int b = d >> 7;
        int pos = atomicAdd(&cur[b], 1);
        ebuf[pos] = src[i] | ((d & 127) << 17);
    }
}

// Epilogue for one node: normalize, +b1, ELU, @W2, layer-2 logits, pack h2pad.
__device__ __forceinline__ void l1_epilogue(
    int node, int t, float den,
    float a0, float a1, float a2, float a3,
    float a4, float a5, float a6, float a7,
    const float* __restrict__ b1, const float* __restrict__ W2,
    const float* __restrict__ a_src2, const float* __restrict__ a_dst2,
    float* __restrict__ h2pad, float* __restrict__ asrc2,
    float* __restrict__ adst2, float* __restrict__ eloop2) {
    float inv = 1.f / den;
    const float4* b1v = (const float4*)b1;
    float4 bA = b1v[t * 2], bB = b1v[t * 2 + 1];
    float v0 = a0 * inv + bA.x, v1 = a1 * inv + bA.y;
    float v2 = a2 * inv + bA.z, v3 = a3 * inv + bA.w;
    float v4 = a4 * inv + bB.x, v5 = a5 * inv + bB.y;
    float v6 = a6 * inv + bB.z, v7 = a7 * inv + bB.w;
    v0 = v0 > 0.f ? v0 : __expf(v0) - 1.f;
    v1 = v1 > 0.f ? v1 : __expf(v1) - 1.f;
    v2 = v2 > 0.f ? v2 : __expf(v2) - 1.f;
    v3 = v3 > 0.f ? v3 : __expf(v3) - 1.f;
    v4 = v4 > 0.f ? v4 : __expf(v4) - 1.f;
    v5 = v5 > 0.f ? v5 : __expf(v5) - 1.f;
    v6 = v6 > 0.f ? v6 : __expf(v6) - 1.f;
    v7 = v7 > 0.f ? v7 : __expf(v7) - 1.f;

    float hh[6];
    #pragma unroll
    for (int c2 = 0; c2 < 6; c2++) {
        const float* Wc = &W2[(t * 8) * 6 + c2];
        float p = v0 * Wc[0] + v1 * Wc[6] + v2 * Wc[12] + v3 * Wc[18]
                + v4 * Wc[24] + v5 * Wc[30] + v6 * Wc[36] + v7 * Wc[42];
        #pragma unroll
        for (int mm = 4; mm >= 1; mm >>= 1) p += __shfl_xor(p, mm);
        hh[c2] = p;
    }
    float as = 0.f, ad = 0.f;
    #pragma unroll
    for (int c2 = 0; c2 < 6; c2++) {
        as += hh[c2] * a_src2[c2];
        ad += hh[c2] * a_dst2[c2];
    }
    if (t == 0) {
        #pragma unroll
        for (int c2 = 0; c2 < 6; c2++) h2pad[(size_t)node * 8 + c2] = hh[c2];
        h2pad[(size_t)node * 8 + 6] = as;
        asrc2[node] = as;
        adst2[node] = ad;
        eloop2[node] = lrelu(as + ad);
    }
}

// Fused csr-build + EDGE-PARALLEL layer-1 gather. One 512-thread block per
// 128-node bucket. The bucket's 128 output rows live in LDS (acc[128][65],
// +1 pad -> 2-way bank alias only). Phase 2 is a flat loop over the bucket's
// ebuf slice: 64 edges/iter, 8 lanes per edge, ds_add_f32 accumulation —
// no loop-carried dependency, no per-node imbalance.
__global__ void __launch_bounds__(512, 2)
fusedG1(const int* __restrict__ ebuf, const int* __restrict__ ocounts,
        const unsigned* __restrict__ gmax1,
        const __half* __restrict__ h1h, const float* __restrict__ asrc1,
        const float* __restrict__ adst1, const float* __restrict__ eloop1,
        const float* __restrict__ b1, const float* __restrict__ W2,
        const float* __restrict__ a_src2, const float* __restrict__ a_dst2,
        int* __restrict__ rowstart, int* __restrict__ deg, int* __restrict__ csr,
        float* __restrict__ h2pad, float* __restrict__ asrc2,
        float* __restrict__ adst2, float* __restrict__ eloop2,
        int N, int E, int G, int nbuck) {
    int b = blockIdx.x;
    int beg = ocounts[b * G];
    int end = (b + 1 < nbuck) ? ocounts[(b + 1) * G] : E;
    int base = b << 7;
    int tid = threadIdx.x;

    __shared__ int cnt[128], sc[128], rloc[128], lcur[128];
    __shared__ float adhT[512], mT[512], denT[128 * 5];
    __shared__ float acc[128 * 65];

    if (tid < 128) cnt[tid] = 0;
    __syncthreads();
    for (int i = beg + tid; i < end; i += 512)
        atomicAdd(&cnt[ebuf[i] >> 17], 1);
    __syncthreads();
    if (tid < 128) sc[tid] = cnt[tid];
    __syncthreads();
    for (int off = 1; off < 128; off <<= 1) {
        int t = (tid < 128) ? sc[tid] : 0;
        int add = (tid >= off && tid < 128) ? sc[tid - off] : 0;
        __syncthreads();
        if (tid < 128) sc[tid] = t + add;
        __syncthreads();
    }
    if (tid < 128) {
        int ex = sc[tid] - cnt[tid];         // bucket-local exclusive scan
        rloc[tid] = beg + ex;
        lcur[tid] = 0;
        int node = base + tid;
        if (node < N) { rowstart[node] = beg + ex; deg[node] = cnt[tid]; }
    }
    // per-(node,head) tables: adh, bound m, den seeded with self-loop z0
    {
        int j = tid >> 2, h = tid & 3;
        int node = base + j;
        if (node < N) {
            float adh = adst1[node * 4 + h];
            float m = lrelu(decf(gmax1[h]) + adh);
            adhT[tid] = adh;
            mT[tid] = m;
            denT[j * 5 + h] = __expf(eloop1[node * 4 + h] - m);
        }
    }
    __syncthreads();

    // csr scatter to global (needed by gatherL2)
    for (int i = beg + tid; i < end; i += 512) {
        int e = ebuf[i];
        int j = e >> 17;
        int pos = atomicAdd(&lcur[j], 1);
        csr[rloc[j] + pos] = e & 0x1FFFF;
    }

    // acc init: acc[nl][ch] = z0 * h1[node][ch]  (8 lanes per node, 2 rounds)
    const uint4* h1v = (const uint4*)h1h;    // fp16 row = 8 uint4 (128B)
    int t = tid & 7;
    int head = t >> 1;
    #pragma unroll
    for (int round = 0; round < 2; ++round) {
        int nl = round * 64 + (tid >> 3);
        int node = base + nl;
        if (node < N) {
            float z0 = denT[nl * 5 + head];
            uint4 hv = h1v[(size_t)node * 8 + t];
            float2 f0 = __half22float2(*(const __half2*)&hv.x);
            float2 f1 = __half22float2(*(const __half2*)&hv.y);
            float2 f2 = __half22float2(*(const __half2*)&hv.z);
            float2 f3 = __half22float2(*(const __half2*)&hv.w);
            float* arow = &acc[nl * 65 + t * 8];
            arow[0] = z0 * f0.x; arow[1] = z0 * f0.y;
            arow[2] = z0 * f1.x; arow[3] = z0 * f1.y;
            arow[4] = z0 * f2.x; arow[5] = z0 * f2.y;
            arow[6] = z0 * f3.x; arow[7] = z0 * f3.y;
        }
    }
    __syncthreads();

    // ---- Phase 2: edge-parallel gather, 8 lanes per edge, depth-1 prefetch ----
    {
        int i0 = beg + (tid >> 3);
        bool v0 = i0 < end;
        int e0 = v0 ? ebuf[i0] : 0;
        int j0 = e0 >> 17, s0 = e0 & 0x1FFFF;
        float av0 = v0 ? asrc1[s0 * 4 + head] : 0.f;
        uint4 hr0 = v0 ? h1v[(size_t)s0 * 8 + t] : make_uint4(0, 0, 0, 0);
        int nIter = (end - beg + 63) >> 6;
        for (int it = 0; it < nIter; ++it) {
            int i1 = i0 + 64;
            bool v1 = i1 < end;
            int e1 = v1 ? ebuf[i1] : 0;
            int j1 = e1 >> 17, s1 = e1 & 0x1FFFF;
            float av1 = v1 ? asrc1[s1 * 4 + head] : 0.f;
            uint4 hr1 = v1 ? h1v[(size_t)s1 * 8 + t] : make_uint4(0, 0, 0, 0);
            if (v0) {
                float z = __expf(lrelu(av0 + adhT[j0 * 4 + head]) - mT[j0 * 4 + head]);
                float2 g0 = __half22float2(*(const __half2*)&hr0.x);
                float2 g1 = __half22float2(*(const __half2*)&hr0.y);
                float2 g2 = __half22float2(*(const __half2*)&hr0.z);
                float2 g3 = __half22float2(*(const __half2*)&hr0.w);
                float* arow = &acc[j0 * 65 + t * 8];
                atomicAdd(&arow[0], z * g0.x); atomicAdd(&arow[1], z * g0.y);
                atomicAdd(&arow[2], z * g1.x); atomicAdd(&arow[3], z * g1.y);
                atomicAdd(&arow[4], z * g2.x); atomicAdd(&arow[5], z * g2.y);
                atomicAdd(&arow[6], z * g3.x); atomicAdd(&arow[7], z * g3.y);
                if ((t & 1) == 0) atomicAdd(&denT[j0 * 5 + head], z);
            }
            i0 = i1; v0 = v1; j0 = j1; av0 = av1; hr0 = hr1;
        }
    }
    __syncthreads();

    // ---- Epilogue per node (8 lanes per node, 2 rounds) ----
    #pragma unroll
    for (int round = 0; round < 2; ++round) {
        int nl = round * 64 + (tid >> 3);
        int node = base + nl;
        if (node >= N) continue;
        float den = denT[nl * 5 + head];
        const float* arow = &acc[nl * 65 + t * 8];
        l1_epilogue(node, t, den,
                    arow[0], arow[1], arow[2], arow[3],
                    arow[4], arow[5], arow[6], arow[7],
                    b1, W2, a_src2, a_dst2, h2pad, asrc2, adst2, eloop2);
    }
}

// Layer-2 gather + log_softmax. 32 lanes per node (2 nodes/wave, 8 per block).
__global__ void gatherL2(const int* __restrict__ csr, const int* __restrict__ rowstart,
                         const int* __restrict__ deg, const unsigned* __restrict__ gmax2,
                         const float* __restrict__ h2pad, const float* __restrict__ adst2,
                         const float* __restrict__ eloop2,
                         const float* __restrict__ b2, float* __restrict__ out, int N) {
    int node = blockIdx.x * 8 + (threadIdx.x >> 5);
    if (node >= N) return;
    int lane = threadIdx.x & 31;
    int rs = rowstart[node], ke = rs + deg[node];

    float adn = adst2[node];
    float m = lrelu(decf(*gmax2) + adn);

    float den = 0.f;
    float a0 = 0.f, a1 = 0.f, a2 = 0.f, a3 = 0.f, a4 = 0.f, a5 = 0.f;
    if (lane == 0) {
        float z0 = __expf(eloop2[node] - m);
        den = z0;
        float4 lo = ((const float4*)h2pad)[(size_t)node * 2];
        float4 hi = ((const float4*)h2pad)[(size_t)node * 2 + 1];
        a0 = z0 * lo.x; a1 = z0 * lo.y; a2 = z0 * lo.z;
        a3 = z0 * lo.w; a4 = z0 * hi.x; a5 = z0 * hi.y;
    }
    for (int k = rs + lane; k < ke; k += 32) {
        int s = csr[k];
        float4 lo = ((const float4*)h2pad)[(size_t)s * 2];
        float4 hi = ((const float4*)h2pad)[(size_t)s * 2 + 1];
        float z = __expf(lrelu(hi.z + adn) - m);   // hi.z = asrc2[s]
        den += z;
        a0 = fmaf(z, lo.x, a0); a1 = fmaf(z, lo.y, a1); a2 = fmaf(z, lo.z, a2);
        a3 = fmaf(z, lo.w, a3); a4 = fmaf(z, hi.x, a4); a5 = fmaf(z, hi.y, a5);
    }
    #pragma unroll
    for (int mm = 16; mm >= 1; mm >>= 1) {
        den += __shfl_xor(den, mm);
        a0 += __shfl_xor(a0, mm); a1 += __shfl_xor(a1, mm); a2 += __shfl_xor(a2, mm);
        a3 += __shfl_xor(a3, mm); a4 += __shfl_xor(a4, mm); a5 += __shfl_xor(a5, mm);
    }
    if (lane == 0) {
        float inv = 1.f / den;
        float v[6] = { a0 * inv + b2[0], a1 * inv + b2[1], a2 * inv + b2[2],
                       a3 * inv + b2[3], a4 * inv + b2[4], a5 * inv + b2[5] };
        float mxv = -1e30f;
        #pragma unroll
        for (int cc = 0; cc < 6; cc++) mxv = fmaxf(mxv, v[cc]);
        float ssum = 0.f;
        #pragma unroll
        for (int cc = 0; cc < 6; cc++) ssum += __expf(v[cc] - mxv);
        float lse = mxv + logf(ssum);
        #pragma unroll
        for (int cc = 0; cc < 6; cc++) out[node * 6 + cc] = v[cc] - lse;
    }
}

extern "C" void kernel_launch(void* const* d_in, const int* in_sizes, int n_in,
                              void* d_out, int out_size, void* d_ws, size_t ws_size,
                              hipStream_t stream) {
    const float* x      = (const float*)d_in[0];
    const int*   ei     = (const int*)d_in[1];
    const float* W1     = (const float*)d_in[2];
    const float* a_src1 = (const float*)d_in[3];
    const float* a_dst1 = (const float*)d_in[4];
    const float* b1     = (const float*)d_in[5];
    const float* W2     = (const float*)d_in[6];
    const float* a_src2 = (const float*)d_in[7];
    const float* a_dst2 = (const float*)d_in[8];
    const float* b2     = (const float*)d_in[9];
    float* out = (float*)d_out;

    const int N = in_sizes[0] / 7;
    const int E = in_sizes[1] / 2;
    const int* src = ei;
    const int* dst = ei + E;
    const int nbuck = (N + 127) >> 7;
    const int G = 256;                      // sort blocks
    const int M = nbuck * G;                // counts entries (<= 262144)

    // Workspace layout
    float* w = (float*)d_ws;
    __half* h1h  = (__half*)w;  w += (size_t)N * 32;   // N*64 halves
    float* asrc1  = w;  w += (size_t)N * 4;
    float* adst1  = w;  w += (size_t)N * 4;
    float* eloop1 = w;  w += (size_t)N * 4;
    float* h2pad  = w;  w += (size_t)N * 8;
    float* asrc2  = w;  w += (size_t)N;
    float* adst2  = w;  w += (size_t)N;
    float* eloop2 = w;  w += (size_t)N;
    int* ip = (int*)w;
    int* ebuf     = ip; ip += E;
    int* deg      = ip; ip += N;
    int* rowstart = ip; ip += N;
    int* blockSum = ip; ip += 1024;
    int* csr      = ip; ip += E;
    int* counts   = ip; ip += M;
    int* ocounts  = ip; ip += M;
    unsigned* gmax1 = (unsigned*)ip; ip += 4;
    unsigned* gmax2 = (unsigned*)ip; ip += 4;

    const int B = 256;
    int nbM = (M + 255) / 256;

    // merged phaseA + dst histogram (grid must equal G)
    phaseAH<<<dim3(G), 512, 0, stream>>>(x, W1, a_src1, a_dst1, dst,
                                         h1h, asrc1, adst1, eloop1,
                                         counts, gmax1, gmax2, N, E, nbuck);
    gmax1K<<<128, B, 0, stream>>>(asrc1, gmax1, N);
    scan1<<<dim3(nbM), 256, 0, stream>>>(counts, ocounts, blockSum, M);
    scan2<<<1, 1024, 0, stream>>>(blockSum, nbM);
    scan3<<<dim3(nbM), 256, 0, stream>>>(ocounts, blockSum, M);
    scatterS<<<dim3(G), 512, 0, stream>>>(src, dst, ocounts, ebuf, E, nbuck);
    // fused csr-build + edge-parallel layer-1 gather (LDS accumulators)
    fusedG1<<<dim3(nbuck), 512, 0, stream>>>(ebuf, ocounts, gmax1,
                                             h1h, asrc1, adst1, eloop1,
                                             b1, W2, a_src2, a_dst2,
                                             rowstart, deg, csr,
                                             h2pad, asrc2, adst2, eloop2,
                                             N, E, G, nbuck);
    gmax2K<<<128, B, 0, stream>>>(asrc2, gmax2, N);
    gatherL2<<<dim3((N + 7) / 8), B, 0, stream>>>(csr, rowstart, deg, gmax2,
                                                  h2pad, adst2, eloop2, b2, out, N);
}

// Round 14
// 222.525 us; speedup vs baseline: 7.1014x; 7.1014x over previous
//
#include <hip/hip_runtime.h>
#include <hip/hip_fp16.h>
#include <math.h>

#define NEG_SLOPE 0.2f
#define LCAP 8192   // LDS csr capacity per bucket (avg 4096, max ~4500)

__device__ __forceinline__ float lrelu(float x) { return x > 0.f ? x : NEG_SLOPE * x; }

// Order-preserving float<->uint encoding so unsigned atomicMax == float max.
// 0u is a safe bottom element (below every finite encoding).
__device__ __forceinline__ unsigned encf(float f) {
    unsigned u = __float_as_uint(f);
    return (u & 0x80000000u) ? ~u : (u | 0x80000000u);
}
__device__ __forceinline__ float decf(unsigned u) {
    return __uint_as_float((u & 0x80000000u) ? (u ^ 0x80000000u) : ~u);
}

// Phase A + dst-histogram + gmax1 block-reduction (merged).
// Grid MUST be G=256 blocks x 512 threads: counts[j*G + blockIdx] layout is
// shared with scatterS. gmax1 must be zeroed (memset) before this kernel.
__global__ void __launch_bounds__(512)
phaseAH(const float* __restrict__ x, const float* __restrict__ W1,
        const float* __restrict__ a_src, const float* __restrict__ a_dst,
        const int* __restrict__ dst,
        __half* __restrict__ h1h, float* __restrict__ asrc1,
        float* __restrict__ adst1, float* __restrict__ eloop1,
        int* __restrict__ counts, unsigned* __restrict__ gmax1,
        int N, int E, int nbuck) {
    __shared__ int hist[1024];
    __shared__ unsigned bmax1[4];
    int tid = threadIdx.x;
    for (int j = tid; j < nbuck; j += 512) hist[j] = 0;
    if (tid < 4) bmax1[tid] = 0u;
    __syncthreads();

    // histogram over this block's edge slice
    int per = (E + gridDim.x - 1) / gridDim.x;
    int i0 = blockIdx.x * per, i1 = min(E, i0 + per);
    for (int i = i0 + tid; i < i1; i += 512)
        atomicAdd(&hist[dst[i] >> 7], 1);

    // phaseA over this block's node slice (wave per node)
    int npb = (N + gridDim.x - 1) / gridDim.x;
    int n0 = blockIdx.x * npb, n1 = min(N, n0 + npb);
    int lane = tid & 63;
    int head = lane >> 4, c = lane & 15;
    for (int node = n0 + (tid >> 6); node < n1; node += 8) {
        float h = 0.f;
        #pragma unroll
        for (int k = 0; k < 7; k++) h += x[node * 7 + k] * W1[k * 64 + lane];

        float ho = __shfl_xor(h, 1);
        if (!(lane & 1)) {
            __half2 hp = __floats2half2_rn(h, ho);
            ((__half2*)h1h)[(size_t)node * 32 + (lane >> 1)] = hp;
        }

        float s = h * a_src[lane];
        float d = h * a_dst[lane];
        #pragma unroll
        for (int m = 8; m >= 1; m >>= 1) {
            s += __shfl_xor(s, m);
            d += __shfl_xor(d, m);
        }
        if (c == 0) {
            asrc1[node * 4 + head] = s;
            adst1[node * 4 + head] = d;
            eloop1[node * 4 + head] = lrelu(s + d);
            atomicMax(&bmax1[head], encf(s));   // LDS block-level max
        }
    }
    __syncthreads();
    for (int j = tid; j < nbuck; j += 512)
        counts[j * gridDim.x + blockIdx.x] = hist[j];
    if (tid < 4) atomicMax(&gmax1[tid], bmax1[tid]);
}

// Exclusive scan over counts (2 kernels; scan3's add is folded into consumers).
__global__ void scan1(const int* __restrict__ in, int* __restrict__ outv,
                      int* __restrict__ blockSum, int n) {
    __shared__ int sm[256];
    int tid = threadIdx.x;
    int i = blockIdx.x * 256 + tid;
    int v = (i < n) ? in[i] : 0;
    sm[tid] = v;
    __syncthreads();
    for (int off = 1; off < 256; off <<= 1) {
        int t = sm[tid];
        int add = (tid >= off) ? sm[tid - off] : 0;
        __syncthreads();
        sm[tid] = t + add;
        __syncthreads();
    }
    if (i < n) outv[i] = sm[tid] - v;     // block-local exclusive
    if (tid == 255) blockSum[blockIdx.x] = sm[255];
}

__global__ void scan2(int* __restrict__ blockSum, int nb) {
    __shared__ int sm[1024];
    int tid = threadIdx.x;
    int v = (tid < nb) ? blockSum[tid] : 0;
    sm[tid] = v;
    __syncthreads();
    for (int off = 1; off < 1024; off <<= 1) {
        int t = sm[tid];
        int add = (tid >= off) ? sm[tid - off] : 0;
        __syncthreads();
        sm[tid] = t + add;
        __syncthreads();
    }
    if (tid < nb) blockSum[tid] = sm[tid] - v;  // exclusive
}

// scatterS: LDS cursors seeded from (ocounts + blockSum); LDS atomics only.
// ebuf entry packed: src (17b) | local-node-id (7b) << 17.
__global__ void scatterS(const int* __restrict__ src, const int* __restrict__ dst,
                         const int* __restrict__ ocounts, const int* __restrict__ blockSum,
                         int* __restrict__ ebuf, int E, int nbuck) {
    __shared__ int cur[1024];
    for (int j = threadIdx.x; j < nbuck; j += blockDim.x) {
        int idx = j * gridDim.x + blockIdx.x;
        cur[j] = ocounts[idx] + blockSum[idx >> 8];
    }
    __syncthreads();
    int per = (E + gridDim.x - 1) / gridDim.x;
    int i0 = blockIdx.x * per, i1 = min(E, i0 + per);
    for (int i = i0 + threadIdx.x; i < i1; i += blockDim.x) {
        int d = dst[i];
        int b = d >> 7;
        int pos = atomicAdd(&cur[b], 1);
        ebuf[pos] = src[i] | ((d & 127) << 17);
    }
}

// Epilogue for one node: normalize, +b1, ELU, @W2, layer-2 logits, pack h2pad.
// Also folds the block-level asrc2 max (for gmax2) into LDS.
__device__ __forceinline__ void l1_epilogue(
    int node, int t, float den,
    float a0, float a1, float a2, float a3,
    float a4, float a5, float a6, float a7,
    const float* __restrict__ b1, const float* __restrict__ W2,
    const float* __restrict__ a_src2, const float* __restrict__ a_dst2,
    float* __restrict__ h2pad, float* __restrict__ asrc2,
    float* __restrict__ adst2, float* __restrict__ eloop2,
    unsigned* bmax2s) {
    float inv = 1.f / den;
    const float4* b1v = (const float4*)b1;
    float4 bA = b1v[t * 2], bB = b1v[t * 2 + 1];
    float v0 = a0 * inv + bA.x, v1 = a1 * inv + bA.y;
    float v2 = a2 * inv + bA.z, v3 = a3 * inv + bA.w;
    float v4 = a4 * inv + bB.x, v5 = a5 * inv + bB.y;
    float v6 = a6 * inv + bB.z, v7 = a7 * inv + bB.w;
    v0 = v0 > 0.f ? v0 : __expf(v0) - 1.f;
    v1 = v1 > 0.f ? v1 : __expf(v1) - 1.f;
    v2 = v2 > 0.f ? v2 : __expf(v2) - 1.f;
    v3 = v3 > 0.f ? v3 : __expf(v3) - 1.f;
    v4 = v4 > 0.f ? v4 : __expf(v4) - 1.f;
    v5 = v5 > 0.f ? v5 : __expf(v5) - 1.f;
    v6 = v6 > 0.f ? v6 : __expf(v6) - 1.f;
    v7 = v7 > 0.f ? v7 : __expf(v7) - 1.f;

    float hh[6];
    #pragma unroll
    for (int c2 = 0; c2 < 6; c2++) {
        const float* Wc = &W2[(t * 8) * 6 + c2];
        float p = v0 * Wc[0] + v1 * Wc[6] + v2 * Wc[12] + v3 * Wc[18]
                + v4 * Wc[24] + v5 * Wc[30] + v6 * Wc[36] + v7 * Wc[42];
        #pragma unroll
        for (int mm = 4; mm >= 1; mm >>= 1) p += __shfl_xor(p, mm);
        hh[c2] = p;
    }
    float as = 0.f, ad = 0.f;
    #pragma unroll
    for (int c2 = 0; c2 < 6; c2++) {
        as += hh[c2] * a_src2[c2];
        ad += hh[c2] * a_dst2[c2];
    }
    if (t == 0) {
        #pragma unroll
        for (int c2 = 0; c2 < 6; c2++) h2pad[(size_t)node * 8 + c2] = hh[c2];
        h2pad[(size_t)node * 8 + 6] = as;
        asrc2[node] = as;
        adst2[node] = ad;
        eloop2[node] = lrelu(as + ad);
        atomicMax(bmax2s, encf(as));     // LDS block-level max for gmax2
    }
}

// Fused csr-build + layer-1 gather + gmax2 block-reduction.
// One 512-thread block per 128-node bucket. Phase 1: build the bucket's csr
// in LDS (and stream to global for gatherL2). Phase 2: per-half sequential
// gather, 8 lanes per node, depth-2 branch-free software pipeline.
__global__ void __launch_bounds__(512, 2)
fusedG1(const int* __restrict__ ebuf, const int* __restrict__ ocounts,
        const int* __restrict__ blockSum, const unsigned* __restrict__ gmax1,
        const __half* __restrict__ h1h, const float* __restrict__ asrc1,
        const float* __restrict__ adst1, const float* __restrict__ eloop1,
        const float* __restrict__ b1, const float* __restrict__ W2,
        const float* __restrict__ a_src2, const float* __restrict__ a_dst2,
        int* __restrict__ rowstart, int* __restrict__ deg, int* __restrict__ csr,
        float* __restrict__ h2pad, float* __restrict__ asrc2,
        float* __restrict__ adst2, float* __restrict__ eloop2,
        unsigned* __restrict__ gmax2, int N, int E, int G, int nbuck) {
    int b = blockIdx.x;
    int idxb = b * G;
    int beg = ocounts[idxb] + blockSum[idxb >> 8];
    int end = E;
    if (b + 1 < nbuck) {
        int idx2 = (b + 1) * G;
        end = ocounts[idx2] + blockSum[idx2 >> 8];
    }
    int base = b << 7;
    int tid = threadIdx.x;

    __shared__ int cnt[128], sc[128], rloc[128], lloc[128], lcur[128];
    __shared__ int lcsr[LCAP];
    __shared__ unsigned bmax2s;

    if (tid == 0) bmax2s = 0u;
    if (tid < 128) cnt[tid] = 0;
    __syncthreads();
    for (int i = beg + tid; i < end; i += blockDim.x)
        atomicAdd(&cnt[ebuf[i] >> 17], 1);
    __syncthreads();
    if (tid < 128) sc[tid] = cnt[tid];
    __syncthreads();
    for (int off = 1; off < 128; off <<= 1) {
        int t = (tid < 128) ? sc[tid] : 0;
        int add = (tid >= off && tid < 128) ? sc[tid - off] : 0;
        __syncthreads();
        if (tid < 128) sc[tid] = t + add;
        __syncthreads();
    }
    if (tid < 128) {
        int ex = sc[tid] - cnt[tid];         // bucket-local exclusive scan
        lloc[tid] = ex;
        rloc[tid] = beg + ex;
        lcur[tid] = 0;
        int node = base + tid;
        if (node < N) { rowstart[node] = beg + ex; deg[node] = cnt[tid]; }
    }
    __syncthreads();
    for (int i = beg + tid; i < end; i += blockDim.x) {
        int e = ebuf[i];
        int j = e >> 17;
        int s = e & 0x1FFFF;
        int pos = atomicAdd(&lcur[j], 1);
        int li = lloc[j] + pos;
        if (li < LCAP) lcsr[li] = s;
        csr[rloc[j] + pos] = s;              // global copy for gatherL2
    }
    __syncthreads();

    // ---- Phase 2: layer-1 gather, depth-2 pipelined ----
    const uint4* h1v = (const uint4*)h1h;    // fp16 row = 8 uint4 (128B)
    int t = tid & 7;
    int head = t >> 1;
    #pragma unroll
    for (int half = 0; half < 2; ++half) {
        int nl = half * 64 + (tid >> 3);     // local node 0..127
        int node = base + nl;
        if (node >= N) continue;
        int rs = lloc[nl], dg = cnt[nl];
        int grs = rloc[nl];

        float adh = adst1[node * 4 + head];
        float el = eloop1[node * 4 + head];
        float m = lrelu(decf(gmax1[head]) + adh);

        float z0 = __expf(el - m);
        float den = z0;
        uint4 hv0 = h1v[(size_t)node * 8 + t];
        float2 f0 = __half22float2(*(const __half2*)&hv0.x);
        float2 f1 = __half22float2(*(const __half2*)&hv0.y);
        float2 f2 = __half22float2(*(const __half2*)&hv0.z);
        float2 f3 = __half22float2(*(const __half2*)&hv0.w);
        float a0 = z0 * f0.x, a1 = z0 * f0.y, a2 = z0 * f1.x, a3 = z0 * f1.y;
        float a4 = z0 * f2.x, a5 = z0 * f2.y, a6 = z0 * f3.x, a7 = z0 * f3.y;

        if (dg > 0) {
            // prime pipeline: edges 0 and 1 (clamped)
            int i1c = (dg > 1) ? 1 : 0;
            int sA = (rs < LCAP) ? lcsr[rs] : csr[grs];
            int liB = rs + i1c;
            int sB = (liB < LCAP) ? lcsr[liB] : csr[grs + i1c];
            float avA = asrc1[sA * 4 + head];
            uint4 hrA = h1v[(size_t)sA * 8 + t];
            float avB = asrc1[sB * 4 + head];
            uint4 hrB = h1v[(size_t)sB * 8 + t];
            for (int k = 0; k < dg; ++k) {
                int k2 = (k + 2 < dg) ? k + 2 : dg - 1;
                int liC = rs + k2;
                int sC = (liC < LCAP) ? lcsr[liC] : csr[grs + k2];
                float avC = asrc1[sC * 4 + head];
                uint4 hrC = h1v[(size_t)sC * 8 + t];
                float z = __expf(lrelu(avA + adh) - m);
                den += z;
                float2 g0 = __half22float2(*(const __half2*)&hrA.x);
                float2 g1 = __half22float2(*(const __half2*)&hrA.y);
                float2 g2 = __half22float2(*(const __half2*)&hrA.z);
                float2 g3 = __half22float2(*(const __half2*)&hrA.w);
                a0 = fmaf(z, g0.x, a0); a1 = fmaf(z, g0.y, a1);
                a2 = fmaf(z, g1.x, a2); a3 = fmaf(z, g1.y, a3);
                a4 = fmaf(z, g2.x, a4); a5 = fmaf(z, g2.y, a5);
                a6 = fmaf(z, g3.x, a6); a7 = fmaf(z, g3.y, a7);
                avA = avB; hrA = hrB;
                avB = avC; hrB = hrC;
            }
        }

        l1_epilogue(node, t, den, a0, a1, a2, a3, a4, a5, a6, a7,
                    b1, W2, a_src2, a_dst2, h2pad, asrc2, adst2, eloop2,
                    &bmax2s);
    }
    __syncthreads();
    if (tid == 0) atomicMax(gmax2, bmax2s);
}

// Layer-2 gather + log_softmax. 32 lanes per node (2 nodes/wave, 8 per block).
__global__ void gatherL2(const int* __restrict__ csr, const int* __restrict__ rowstart,
                         const int* __restrict__ deg, const unsigned* __restrict__ gmax2,
                         const float* __restrict__ h2pad, const float* __restrict__ adst2,
                         const float* __restrict__ eloop2,
                         const float* __restrict__ b2, float* __restrict__ out, int N) {
    int node = blockIdx.x * 8 + (threadIdx.x >> 5);
    if (node >= N) return;
    int lane = threadIdx.x & 31;
    int rs = rowstart[node], ke = rs + deg[node];

    float adn = adst2[node];
    float m = lrelu(decf(*gmax2) + adn);

    float den = 0.f;
    float a0 = 0.f, a1 = 0.f, a2 = 0.f, a3 = 0.f, a4 = 0.f, a5 = 0.f;
    if (lane == 0) {
        float z0 = __expf(eloop2[node] - m);
        den = z0;
        float4 lo = ((const float4*)h2pad)[(size_t)node * 2];
        float4 hi = ((const float4*)h2pad)[(size_t)node * 2 + 1];
        a0 = z0 * lo.x; a1 = z0 * lo.y; a2 = z0 * lo.z;
        a3 = z0 * lo.w; a4 = z0 * hi.x; a5 = z0 * hi.y;
    }
    for (int k = rs + lane; k < ke; k += 32) {
        int s = csr[k];
        float4 lo = ((const float4*)h2pad)[(size_t)s * 2];
        float4 hi = ((const float4*)h2pad)[(size_t)s * 2 + 1];
        float z = __expf(lrelu(hi.z + adn) - m);   // hi.z = asrc2[s]
        den += z;
        a0 = fmaf(z, lo.x, a0); a1 = fmaf(z, lo.y, a1); a2 = fmaf(z, lo.z, a2);
        a3 = fmaf(z, lo.w, a3); a4 = fmaf(z, hi.x, a4); a5 = fmaf(z, hi.y, a5);
    }
    #pragma unroll
    for (int mm = 16; mm >= 1; mm >>= 1) {
        den += __shfl_xor(den, mm);
        a0 += __shfl_xor(a0, mm); a1 += __shfl_xor(a1, mm); a2 += __shfl_xor(a2, mm);
        a3 += __shfl_xor(a3, mm); a4 += __shfl_xor(a4, mm); a5 += __shfl_xor(a5, mm);
    }
    if (lane == 0) {
        float inv = 1.f / den;
        float v[6] = { a0 * inv + b2[0], a1 * inv + b2[1], a2 * inv + b2[2],
                       a3 * inv + b2[3], a4 * inv + b2[4], a5 * inv + b2[5] };
        float mxv = -1e30f;
        #pragma unroll
        for (int cc = 0; cc < 6; cc++) mxv = fmaxf(mxv, v[cc]);
        float ssum = 0.f;
        #pragma unroll
        for (int cc = 0; cc < 6; cc++) ssum += __expf(v[cc] - mxv);
        float lse = mxv + logf(ssum);
        #pragma unroll
        for (int cc = 0; cc < 6; cc++) out[node * 6 + cc] = v[cc] - lse;
    }
}

extern "C" void kernel_launch(void* const* d_in, const int* in_sizes, int n_in,
                              void* d_out, int out_size, void* d_ws, size_t ws_size,
                              hipStream_t stream) {
    const float* x      = (const float*)d_in[0];
    const int*   ei     = (const int*)d_in[1];
    const float* W1     = (const float*)d_in[2];
    const float* a_src1 = (const float*)d_in[3];
    const float* a_dst1 = (const float*)d_in[4];
    const float* b1     = (const float*)d_in[5];
    const float* W2     = (const float*)d_in[6];
    const float* a_src2 = (const float*)d_in[7];
    const float* a_dst2 = (const float*)d_in[8];
    const float* b2     = (const float*)d_in[9];
    float* out = (float*)d_out;

    const int N = in_sizes[0] / 7;
    const int E = in_sizes[1] / 2;
    const int* src = ei;
    const int* dst = ei + E;
    const int nbuck = (N + 127) >> 7;
    const int G = 256;                      // sort blocks
    const int M = nbuck * G;                // counts entries (<= 262144)

    // Workspace layout
    float* w = (float*)d_ws;
    __half* h1h  = (__half*)w;  w += (size_t)N * 32;   // N*64 halves
    float* asrc1  = w;  w += (size_t)N * 4;
    float* adst1  = w;  w += (size_t)N * 4;
    float* eloop1 = w;  w += (size_t)N * 4;
    float* h2pad  = w;  w += (size_t)N * 8;
    float* asrc2  = w;  w += (size_t)N;
    float* adst2  = w;  w += (size_t)N;
    float* eloop2 = w;  w += (size_t)N;
    int* ip = (int*)w;
    int* ebuf     = ip; ip += E;
    int* deg      = ip; ip += N;
    int* rowstart = ip; ip += N;
    int* blockSum = ip; ip += 1024;
    int* csr      = ip; ip += E;
    int* counts   = ip; ip += M;
    int* ocounts  = ip; ip += M;
    unsigned* gmax1 = (unsigned*)ip; ip += 4;
    unsigned* gmax2 = (unsigned*)ip; ip += 4;

    int nbM = (M + 255) / 256;

    // zero gmax1[4] + gmax2[1] (encoded bottom = 0u)
    hipMemsetAsync(gmax1, 0, 8 * sizeof(unsigned), stream);
    // merged phaseA + dst histogram + gmax1 reduce (grid must equal G)
    phaseAH<<<dim3(G), 512, 0, stream>>>(x, W1, a_src1, a_dst1, dst,
                                         h1h, asrc1, adst1, eloop1,
                                         counts, gmax1, N, E, nbuck);
    scan1<<<dim3(nbM), 256, 0, stream>>>(counts, ocounts, blockSum, M);
    scan2<<<1, 1024, 0, stream>>>(blockSum, nbM);
    scatterS<<<dim3(G), 512, 0, stream>>>(src, dst, ocounts, blockSum, ebuf, E, nbuck);
    // fused csr-build + layer-1 gather + gmax2 reduce
    fusedG1<<<dim3(nbuck), 512, 0, stream>>>(ebuf, ocounts, blockSum, gmax1,
                                             h1h, asrc1, adst1, eloop1,
                                             b1, W2, a_src2, a_dst2,
                                             rowstart, deg, csr,
                                             h2pad, asrc2, adst2, eloop2,
                                             gmax2, N, E, G, nbuck);
    gatherL2<<<dim3((N + 7) / 8), 256, 0, stream>>>(csr, rowstart, deg, gmax2,
                                                    h2pad, adst2, eloop2, b2, out, N);
}

// Round 15
// 210.883 us; speedup vs baseline: 7.4935x; 1.0552x over previous
//
#include <hip/hip_runtime.h>
#include <math.h>

#define NEG_SLOPE 0.2f

__device__ __forceinline__ float lrelu(float x) { return x > 0.f ? x : NEG_SLOPE * x; }

// Order-preserving float<->uint encoding so unsigned atomicMax == float max.
// 0u is a safe bottom element (below every finite encoding).
__device__ __forceinline__ unsigned encf(float f) {
    unsigned u = __float_as_uint(f);
    return (u & 0x80000000u) ? ~u : (u | 0x80000000u);
}
__device__ __forceinline__ float decf(unsigned u) {
    return __uint_as_float((u & 0x80000000u) ? (u ^ 0x80000000u) : ~u);
}

// Phase A + dst-histogram + gmax1 block-reduction (merged).
// Grid MUST be G=256 blocks x 512 threads: counts[j*G + blockIdx] layout is
// shared with scatterS. gmax1 must be zeroed (memset) before this kernel.
// Writes the packed per-node gather row xa[12] = {x[0..6], asrc1[0..3], pad}.
__global__ void __launch_bounds__(512)
phaseAH(const float* __restrict__ x, const float* __restrict__ W1,
        const float* __restrict__ a_src, const float* __restrict__ a_dst,
        const int* __restrict__ dst,
        float* __restrict__ xa, float* __restrict__ adst1,
        float* __restrict__ eloop1,
        int* __restrict__ counts, unsigned* __restrict__ gmax1,
        int N, int E, int nbuck) {
    __shared__ int hist[1024];
    __shared__ unsigned bmax1[4];
    int tid = threadIdx.x;
    for (int j = tid; j < nbuck; j += 512) hist[j] = 0;
    if (tid < 4) bmax1[tid] = 0u;
    __syncthreads();

    // histogram over this block's edge slice
    int per = (E + gridDim.x - 1) / gridDim.x;
    int i0 = blockIdx.x * per, i1 = min(E, i0 + per);
    for (int i = i0 + tid; i < i1; i += 512)
        atomicAdd(&hist[dst[i] >> 7], 1);

    // phaseA over this block's node slice (wave per node)
    int npb = (N + gridDim.x - 1) / gridDim.x;
    int n0 = blockIdx.x * npb, n1 = min(N, n0 + npb);
    int lane = tid & 63;
    int head = lane >> 4, c = lane & 15;
    for (int node = n0 + (tid >> 6); node < n1; node += 8) {
        float h = 0.f;
        #pragma unroll
        for (int k = 0; k < 7; k++) h += x[node * 7 + k] * W1[k * 64 + lane];

        float s = h * a_src[lane];
        float d = h * a_dst[lane];
        #pragma unroll
        for (int m = 8; m >= 1; m >>= 1) {
            s += __shfl_xor(s, m);
            d += __shfl_xor(d, m);
        }
        if (lane < 7) xa[(size_t)node * 12 + lane] = x[node * 7 + lane];
        if (c == 0) {
            xa[(size_t)node * 12 + 7 + head] = s;
            adst1[node * 4 + head] = d;
            eloop1[node * 4 + head] = lrelu(s + d);
            atomicMax(&bmax1[head], encf(s));   // LDS block-level max
        }
    }
    __syncthreads();
    for (int j = tid; j < nbuck; j += 512)
        counts[j * gridDim.x + blockIdx.x] = hist[j];
    if (tid < 4) atomicMax(&gmax1[tid], bmax1[tid]);
}

// Exclusive scan over counts (2 kernels; scan3's add is folded into consumers).
__global__ void scan1(const int* __restrict__ in, int* __restrict__ outv,
                      int* __restrict__ blockSum, int n) {
    __shared__ int sm[256];
    int tid = threadIdx.x;
    int i = blockIdx.x * 256 + tid;
    int v = (i < n) ? in[i] : 0;
    sm[tid] = v;
    __syncthreads();
    for (int off = 1; off < 256; off <<= 1) {
        int t = sm[tid];
        int add = (tid >= off) ? sm[tid - off] : 0;
        __syncthreads();
        sm[tid] = t + add;
        __syncthreads();
    }
    if (i < n) outv[i] = sm[tid] - v;     // block-local exclusive
    if (tid == 255) blockSum[blockIdx.x] = sm[255];
}

__global__ void scan2(int* __restrict__ blockSum, int nb) {
    __shared__ int sm[1024];
    int tid = threadIdx.x;
    int v = (tid < nb) ? blockSum[tid] : 0;
    sm[tid] = v;
    __syncthreads();
    for (int off = 1; off < 1024; off <<= 1) {
        int t = sm[tid];
        int add = (tid >= off) ? sm[tid - off] : 0;
        __syncthreads();
        sm[tid] = t + add;
        __syncthreads();
    }
    if (tid < nb) blockSum[tid] = sm[tid] - v;  // exclusive
}

// scatterS: LDS cursors seeded from (ocounts + blockSum); LDS atomics only.
// ebuf entry packed: src (17b) | local-node-id (7b) << 17.
__global__ void scatterS(const int* __restrict__ src, const int* __restrict__ dst,
                         const int* __restrict__ ocounts, const int* __restrict__ blockSum,
                         int* __restrict__ ebuf, int E, int nbuck) {
    __shared__ int cur[1024];
    for (int j = threadIdx.x; j < nbuck; j += blockDim.x) {
        int idx = j * gridDim.x + blockIdx.x;
        cur[j] = ocounts[idx] + blockSum[idx >> 8];
    }
    __syncthreads();
    int per = (E + gridDim.x - 1) / gridDim.x;
    int i0 = blockIdx.x * per, i1 = min(E, i0 + per);
    for (int i = i0 + threadIdx.x; i < i1; i += blockDim.x) {
        int d = dst[i];
        int b = d >> 7;
        int pos = atomicAdd(&cur[b], 1);
        ebuf[pos] = src[i] | ((d & 127) << 17);
    }
}

// Fused csr-build + layer-1 gather (xacc-linearized) + epilogue + gmax2 reduce.
// One 512-thread block per 128-node bucket; phase 2 uses 4 lanes per node
// (lane = head), accumulating xacc[7] = sum z*x[s] and den in registers, then
// applies W1/W2 ONCE per node from LDS.
__global__ void __launch_bounds__(512, 2)
fusedG1(const int* __restrict__ ebuf, const int* __restrict__ ocounts,
        const int* __restrict__ blockSum, const unsigned* __restrict__ gmax1,
        const float* __restrict__ xa, const float* __restrict__ adst1,
        const float* __restrict__ eloop1,
        const float* __restrict__ W1, const float* __restrict__ b1,
        const float* __restrict__ W2,
        const float* __restrict__ a_src2, const float* __restrict__ a_dst2,
        int* __restrict__ rowstart, int* __restrict__ deg, int* __restrict__ csr,
        float* __restrict__ h2pad, float* __restrict__ asrc2,
        float* __restrict__ adst2, float* __restrict__ eloop2,
        unsigned* __restrict__ gmax2, int N, int E, int G, int nbuck) {
    int b = blockIdx.x;
    int idxb = b * G;
    int beg = ocounts[idxb] + blockSum[idxb >> 8];
    int end = E;
    if (b + 1 < nbuck) {
        int idx2 = (b + 1) * G;
        end = ocounts[idx2] + blockSum[idx2 >> 8];
    }
    int base = b << 7;
    int tid = threadIdx.x;

    __shared__ int cnt[128], sc[128], rloc[128], lcur[128];
    __shared__ float W1s[448], W2s[384], b1s[64];
    __shared__ unsigned bmax2s;

    if (tid == 0) bmax2s = 0u;
    if (tid < 128) cnt[tid] = 0;
    for (int j = tid; j < 448; j += 512) W1s[j] = W1[j];
    for (int j = tid; j < 384; j += 512) W2s[j] = W2[j];
    if (tid < 64) b1s[tid] = b1[tid];
    __syncthreads();
    for (int i = beg + tid; i < end; i += 512)
        atomicAdd(&cnt[ebuf[i] >> 17], 1);
    __syncthreads();
    if (tid < 128) sc[tid] = cnt[tid];
    __syncthreads();
    for (int off = 1; off < 128; off <<= 1) {
        int t = (tid < 128) ? sc[tid] : 0;
        int add = (tid >= off && tid < 128) ? sc[tid - off] : 0;
        __syncthreads();
        if (tid < 128) sc[tid] = t + add;
        __syncthreads();
    }
    if (tid < 128) {
        int ex = sc[tid] - cnt[tid];         // bucket-local exclusive scan
        rloc[tid] = beg + ex;
        lcur[tid] = 0;
        int node = base + tid;
        if (node < N) { rowstart[node] = beg + ex; deg[node] = cnt[tid]; }
    }
    __syncthreads();
    for (int i = beg + tid; i < end; i += 512) {
        int e = ebuf[i];
        int j = e >> 17;
        int pos = atomicAdd(&lcur[j], 1);
        csr[rloc[j] + pos] = e & 0x1FFFF;    // bucket-window write (L2-local)
    }
    __syncthreads();

    // ---- Phase 2: xacc gather, 4 lanes per node (lane = head), depth-2 ----
    int g = tid >> 2, h = tid & 3;
    int node = base + g;
    if (node < N) {
        int grs = rloc[g], dg = cnt[g];
        float adh = adst1[node * 4 + h];
        float m = lrelu(decf(gmax1[h]) + adh);
        float z0 = __expf(eloop1[node * 4 + h] - m);
        float den = z0;

        const float4* xav = (const float4*)xa;   // row = 3 float4 (48B)
        float4 S0 = xav[(size_t)node * 3];
        float4 S1 = xav[(size_t)node * 3 + 1];
        float xc0 = z0 * S0.x, xc1 = z0 * S0.y, xc2 = z0 * S0.z, xc3 = z0 * S0.w;
        float xc4 = z0 * S1.x, xc5 = z0 * S1.y, xc6 = z0 * S1.z;

        if (dg > 0) {
            int iB = (dg > 1) ? 1 : 0;
            int sA = csr[grs];
            int sB = csr[grs + iB];
            float4 A0 = xav[(size_t)sA * 3], A1 = xav[(size_t)sA * 3 + 1], A2 = xav[(size_t)sA * 3 + 2];
            float4 B0 = xav[(size_t)sB * 3], B1 = xav[(size_t)sB * 3 + 1], B2 = xav[(size_t)sB * 3 + 2];
            for (int k = 0; k < dg; ++k) {
                int k2 = (k + 2 < dg) ? k + 2 : dg - 1;
                int sC = csr[grs + k2];
                float4 C0 = xav[(size_t)sC * 3], C1 = xav[(size_t)sC * 3 + 1], C2 = xav[(size_t)sC * 3 + 2];
                float av = (h == 0) ? A1.w : (h == 1) ? A2.x : (h == 2) ? A2.y : A2.z;
                float z = __expf(lrelu(av + adh) - m);
                den += z;
                xc0 = fmaf(z, A0.x, xc0); xc1 = fmaf(z, A0.y, xc1);
                xc2 = fmaf(z, A0.z, xc2); xc3 = fmaf(z, A0.w, xc3);
                xc4 = fmaf(z, A1.x, xc4); xc5 = fmaf(z, A1.y, xc5);
                xc6 = fmaf(z, A1.z, xc6);
                A0 = B0; A1 = B1; A2 = B2;
                B0 = C0; B1 = C1; B2 = C2;
            }
        }

        // ---- Epilogue: v = (xacc/den)@W1 + b1, ELU, @W2, layer-2 logits ----
        float inv = 1.f / den;
        float xv0 = xc0 * inv, xv1 = xc1 * inv, xv2 = xc2 * inv, xv3 = xc3 * inv;
        float xv4 = xc4 * inv, xv5 = xc5 * inv, xv6 = xc6 * inv;
        float hh[6] = {0.f, 0.f, 0.f, 0.f, 0.f, 0.f};
        #pragma unroll
        for (int c = 0; c < 16; ++c) {
            int ch = h * 16 + c;
            const float* Wc = &W1s[ch];
            float v = xv0 * Wc[0] + xv1 * Wc[64] + xv2 * Wc[128] + xv3 * Wc[192]
                    + xv4 * Wc[256] + xv5 * Wc[320] + xv6 * Wc[384] + b1s[ch];
            v = v > 0.f ? v : __expf(v) - 1.f;   // ELU
            const float* W2c = &W2s[ch * 6];
            #pragma unroll
            for (int c2 = 0; c2 < 6; ++c2) hh[c2] = fmaf(v, W2c[c2], hh[c2]);
        }
        #pragma unroll
        for (int c2 = 0; c2 < 6; ++c2) {
            hh[c2] += __shfl_xor(hh[c2], 1);
            hh[c2] += __shfl_xor(hh[c2], 2);
        }
        float as = 0.f, ad = 0.f;
        #pragma unroll
        for (int c2 = 0; c2 < 6; ++c2) {
            as += hh[c2] * a_src2[c2];
            ad += hh[c2] * a_dst2[c2];
        }
        if (h == 0) {
            #pragma unroll
            for (int c2 = 0; c2 < 6; ++c2) h2pad[(size_t)node * 8 + c2] = hh[c2];
            h2pad[(size_t)node * 8 + 6] = as;
            asrc2[node] = as;
            adst2[node] = ad;
            eloop2[node] = lrelu(as + ad);
            atomicMax(&bmax2s, encf(as));
        }
    }
    __syncthreads();
    if (tid == 0) atomicMax(gmax2, bmax2s);
}

// Layer-2 gather + log_softmax. 32 lanes per node (2 nodes/wave, 8 per block).
__global__ void gatherL2(const int* __restrict__ csr, const int* __restrict__ rowstart,
                         const int* __restrict__ deg, const unsigned* __restrict__ gmax2,
                         const float* __restrict__ h2pad, const float* __restrict__ adst2,
                         const float* __restrict__ eloop2,
                         const float* __restrict__ b2, float* __restrict__ out, int N) {
    int node = blockIdx.x * 8 + (threadIdx.x >> 5);
    if (node >= N) return;
    int lane = threadIdx.x & 31;
    int rs = rowstart[node], ke = rs + deg[node];

    float adn = adst2[node];
    float m = lrelu(decf(*gmax2) + adn);

    float den = 0.f;
    float a0 = 0.f, a1 = 0.f, a2 = 0.f, a3 = 0.f, a4 = 0.f, a5 = 0.f;
    if (lane == 0) {
        float z0 = __expf(eloop2[node] - m);
        den = z0;
        float4 lo = ((const float4*)h2pad)[(size_t)node * 2];
        float4 hi = ((const float4*)h2pad)[(size_t)node * 2 + 1];
        a0 = z0 * lo.x; a1 = z0 * lo.y; a2 = z0 * lo.z;
        a3 = z0 * lo.w; a4 = z0 * hi.x; a5 = z0 * hi.y;
    }
    for (int k = rs + lane; k < ke; k += 32) {
        int s = csr[k];
        float4 lo = ((const float4*)h2pad)[(size_t)s * 2];
        float4 hi = ((const float4*)h2pad)[(size_t)s * 2 + 1];
        float z = __expf(lrelu(hi.z + adn) - m);   // hi.z = asrc2[s]
        den += z;
        a0 = fmaf(z, lo.x, a0); a1 = fmaf(z, lo.y, a1); a2 = fmaf(z, lo.z, a2);
        a3 = fmaf(z, lo.w, a3); a4 = fmaf(z, hi.x, a4); a5 = fmaf(z, hi.y, a5);
    }
    #pragma unroll
    for (int mm = 16; mm >= 1; mm >>= 1) {
        den += __shfl_xor(den, mm);
        a0 += __shfl_xor(a0, mm); a1 += __shfl_xor(a1, mm); a2 += __shfl_xor(a2, mm);
        a3 += __shfl_xor(a3, mm); a4 += __shfl_xor(a4, mm); a5 += __shfl_xor(a5, mm);
    }
    if (lane == 0) {
        float inv = 1.f / den;
        float v[6] = { a0 * inv + b2[0], a1 * inv + b2[1], a2 * inv + b2[2],
                       a3 * inv + b2[3], a4 * inv + b2[4], a5 * inv + b2[5] };
        float mxv = -1e30f;
        #pragma unroll
        for (int cc = 0; cc < 6; cc++) mxv = fmaxf(mxv, v[cc]);
        float ssum = 0.f;
        #pragma unroll
        for (int cc = 0; cc < 6; cc++) ssum += __expf(v[cc] - mxv);
        float lse = mxv + logf(ssum);
        #pragma unroll
        for (int cc = 0; cc < 6; cc++) out[node * 6 + cc] = v[cc] - lse;
    }
}

extern "C" void kernel_launch(void* const* d_in, const int* in_sizes, int n_in,
                              void* d_out, int out_size, void* d_ws, size_t ws_size,
                              hipStream_t stream) {
    const float* x      = (const float*)d_in[0];
    const int*   ei     = (const int*)d_in[1];
    const float* W1     = (const float*)d_in[2];
    const float* a_src1 = (const float*)d_in[3];
    const float* a_dst1 = (const float*)d_in[4];
    const float* b1     = (const float*)d_in[5];
    const float* W2     = (const float*)d_in[6];
    const float* a_src2 = (const float*)d_in[7];
    const float* a_dst2 = (const float*)d_in[8];
    const float* b2     = (const float*)d_in[9];
    float* out = (float*)d_out;

    const int N = in_sizes[0] / 7;
    const int E = in_sizes[1] / 2;
    const int* src = ei;
    const int* dst = ei + E;
    const int nbuck = (N + 127) >> 7;
    const int G = 256;                      // sort blocks
    const int M = nbuck * G;                // counts entries (<= 262144)

    // Workspace layout
    float* w = (float*)d_ws;
    float* xa     = w;  w += (size_t)N * 12;   // packed {x[7], asrc1[4], pad}
    float* adst1  = w;  w += (size_t)N * 4;
    float* eloop1 = w;  w += (size_t)N * 4;
    float* h2pad  = w;  w += (size_t)N * 8;
    float* asrc2  = w;  w += (size_t)N;
    float* adst2  = w;  w += (size_t)N;
    float* eloop2 = w;  w += (size_t)N;
    int* ip = (int*)w;
    int* ebuf     = ip; ip += E;
    int* deg      = ip; ip += N;
    int* rowstart = ip; ip += N;
    int* blockSum = ip; ip += 1024;
    int* csr      = ip; ip += E;
    int* counts   = ip; ip += M;
    int* ocounts  = ip; ip += M;
    unsigned* gmax1 = (unsigned*)ip; ip += 4;
    unsigned* gmax2 = (unsigned*)ip; ip += 4;

    int nbM = (M + 255) / 256;

    // zero gmax1[4] + gmax2 (encoded bottom = 0u)
    hipMemsetAsync(gmax1, 0, 8 * sizeof(unsigned), stream);
    // merged phaseA + dst histogram + gmax1 reduce (grid must equal G)
    phaseAH<<<dim3(G), 512, 0, stream>>>(x, W1, a_src1, a_dst1, dst,
                                         xa, adst1, eloop1,
                                         counts, gmax1, N, E, nbuck);
    scan1<<<dim3(nbM), 256, 0, stream>>>(counts, ocounts, blockSum, M);
    scan2<<<1, 1024, 0, stream>>>(blockSum, nbM);
    scatterS<<<dim3(G), 512, 0, stream>>>(src, dst, ocounts, blockSum, ebuf, E, nbuck);
    // fused csr-build + xacc-linearized layer-1 gather + gmax2 reduce
    fusedG1<<<dim3(nbuck), 512, 0, stream>>>(ebuf, ocounts, blockSum, gmax1,
                                             xa, adst1, eloop1,
                                             W1, b1, W2, a_src2, a_dst2,
                                             rowstart, deg, csr,
                                             h2pad, asrc2, adst2, eloop2,
                                             gmax2, N, E, G, nbuck);
    gatherL2<<<dim3((N + 7) / 8), 256, 0, stream>>>(csr, rowstart, deg, gmax2,
                                                    h2pad, adst2, eloop2, b2, out, N);
}